// Round 1
// baseline (476.330 us; speedup 1.0000x reference)
//
#include <hip/hip_runtime.h>
#include <stdint.h>

#define DEV __device__ __forceinline__

typedef unsigned short u16;
typedef unsigned int u32;

typedef __bf16 bf16x8 __attribute__((ext_vector_type(8)));
typedef float f32x4 __attribute__((ext_vector_type(4)));
typedef u16 u16x8 __attribute__((ext_vector_type(8)));
typedef u16 u16x4 __attribute__((ext_vector_type(4)));

static_assert(sizeof(bf16x8) == 16, "bf16x8 must be 16B");

#define NT 16384      // B*S = 4*4096
#define DM 1024
#define SPAD 4098     // S + 2 halo rows per batch

DEV u16 f2bf(float f) {
  u32 u = __float_as_uint(f);
  u32 r = u + 0x7FFFu + ((u >> 16) & 1u);
  return (u16)(r >> 16);
}
DEV float bf2f(u16 h) { return __uint_as_float(((u32)h) << 16); }
DEV float siluf(float x) { return x / (1.f + __expf(-x)); }
DEV float geluf(float x) { return 0.5f * x * (1.f + erff(x * 0.70710678118654752f)); }

DEV void gload_lds16(const void* g, void* l) {
  __builtin_amdgcn_global_load_lds((const __attribute__((address_space(1))) void*)g,
                                   (__attribute__((address_space(3))) void*)l,
                                   16, 0, 0);
}

// ---------------- converts ----------------
__global__ void cvtk(const float* __restrict__ in, u16* __restrict__ out, int n4, float scale) {
  int i = blockIdx.x * 256 + threadIdx.x;
  if (i >= n4) return;
  const float4 v = *(const float4*)(in + (size_t)i * 4);
  u16x4 o;
  o[0] = f2bf(v.x * scale); o[1] = f2bf(v.y * scale);
  o[2] = f2bf(v.z * scale); o[3] = f2bf(v.w * scale);
  *(u16x4*)(out + (size_t)i * 4) = o;
}

// conv_w [o][d][3] -> Wc [o][tap*1024 + d]
__global__ void cvt_convw(const float* __restrict__ cw, u16* __restrict__ Wc) {
  int i = blockIdx.x * 256 + threadIdx.x;   // 1M threads: o*1024+d
  int o = i >> 10, d = i & 1023;
  const float* src = cw + ((size_t)o * 1024 + d) * 3;
  u16* dst = Wc + (size_t)o * 3072 + d;
  dst[0]    = f2bf(src[0]);
  dst[1024] = f2bf(src[1]);
  dst[2048] = f2bf(src[2]);
}

// zero the 2 halo rows of each batch in Qpad
__global__ void zero_halo(u16* __restrict__ Qpad) {
  int i = blockIdx.x * 256 + threadIdx.x;   // 8192 threads
  int r = i >> 10, c = i & 1023;
  int b = r >> 1, side = r & 1;
  size_t row = (size_t)b * SPAD + (side ? (SPAD - 1) : 0);
  Qpad[row * 1024 + c] = 0;
}

// ---------------- GEMM ----------------
// C[t,n] = sum_k A[t,k] * B[n,k]  (B row-major [N][K] = W as given)
// MODE 0: bf16 out (+bias). MODE 1: bf16 out into Qpad w/ row remap. 
// MODE 2: conv A-addressing (A=Qpad), epilogue gelu(silu(v+bias)) bf16.
// MODE 3: f32 out (+bias).
template<int MODE>
__global__ __launch_bounds__(256, 2)
void gemm_k(const u16* __restrict__ A, const u16* __restrict__ B,
            void* __restrict__ C, const float* __restrict__ bias,
            int M, int N, int K, int lda)
{
  __shared__ alignas(16) char smem[32768];
  char* sA = smem;
  char* sB = smem + 16384;

  int nwg = gridDim.x;
  int bx = blockIdx.x;
  if ((nwg & 7) == 0) bx = (bx & 7) * (nwg >> 3) + (bx >> 3);  // XCD swizzle (bijective)
  int GN = N >> 7;
  int bm = bx / GN, bn = bx - bm * GN;
  int m0 = bm << 7, n0 = bn << 7;

  int tid = threadIdx.x;
  int lane = tid & 63, wid = tid >> 6;
  int wm = wid >> 1, wn = wid & 1;

  f32x4 acc[4][4] = {};

  int strow = tid >> 3;            // 0..31 (row within 32-row chunk per issue)
  int stcolb = (tid & 7) << 4;     // byte col 0..112
  size_t ldab = (size_t)lda * 2;
  size_t ldbb = (size_t)K * 2;
  int bofm = m0 >> 12;             // batch of this m-tile (tiles never straddle batches)

  const int KT = K >> 6;
  for (int kt = 0; kt < KT; ++kt) {
    int k0 = kt << 6;
    const char* Ab;
    if (MODE == 2) {
      int tap = k0 >> 10;
      Ab = (const char*)(A + ((size_t)(m0 + 2 * bofm + tap) * (size_t)lda + (k0 & 1023)));
    } else {
      Ab = (const char*)(A + ((size_t)m0 * (size_t)lda + k0));
    }
    const char* Bb = (const char*)(B + ((size_t)n0 * (size_t)K + k0));
#pragma unroll
    for (int j = 0; j < 4; ++j) {
      int row = j * 32 + strow;
      int sw = (row & 7) << 4;     // XOR swizzle on 16B granules (involution)
      gload_lds16(Ab + (size_t)row * ldab + (size_t)(stcolb ^ sw), sA + j * 4096 + wid * 1024);
      gload_lds16(Bb + (size_t)row * ldbb + (size_t)(stcolb ^ sw), sB + j * 4096 + wid * 1024);
    }
    __syncthreads();
#pragma unroll
    for (int kk = 0; kk < 2; ++kk) {
      bf16x8 av[4], bv[4];
      int cb = ((lane >> 4) << 4) + (kk << 6);
#pragma unroll
      for (int i = 0; i < 4; ++i) {
        int r = (wm << 6) + (i << 4) + (lane & 15);
        av[i] = *(const bf16x8*)(sA + r * 128 + (cb ^ ((r & 7) << 4)));
      }
#pragma unroll
      for (int j = 0; j < 4; ++j) {
        int r = (wn << 6) + (j << 4) + (lane & 15);
        bv[j] = *(const bf16x8*)(sB + r * 128 + (cb ^ ((r & 7) << 4)));
      }
#pragma unroll
      for (int i = 0; i < 4; ++i)
#pragma unroll
        for (int j = 0; j < 4; ++j)
          acc[i][j] = __builtin_amdgcn_mfma_f32_16x16x32_bf16(av[i], bv[j], acc[i][j], 0, 0, 0);
    }
    __syncthreads();
  }

  // epilogue: C row = (lane>>4)*4 + reg, col = lane&15 within 16x16 frag
#pragma unroll
  for (int i = 0; i < 4; ++i) {
    int rb = m0 + (wm << 6) + (i << 4) + ((lane >> 4) << 2);
#pragma unroll
    for (int j = 0; j < 4; ++j) {
      int n = n0 + (wn << 6) + (j << 4) + (lane & 15);
      float bs = bias ? bias[n] : 0.f;
#pragma unroll
      for (int r = 0; r < 4; ++r) {
        int t = rb + r;
        float v = acc[i][j][r] + bs;
        if (MODE == 0) {
          ((u16*)C)[(size_t)t * N + n] = f2bf(v);
        } else if (MODE == 1) {
          size_t row = (size_t)t + 2 * (t >> 12) + 1;   // into Qpad
          ((u16*)C)[row * 1024 + n] = f2bf(v);
        } else if (MODE == 2) {
          ((u16*)C)[(size_t)t * N + n] = f2bf(geluf(siluf(v)));
        } else {
          ((float*)C)[(size_t)t * N + n] = v;
        }
      }
    }
  }
}

// ---------------- softmax-weighted column sum ----------------
// logits[t,e] bf16, vals[t,e] bf16 (optionally row-remapped into Qpad layout)
// per (b,e): m=max_s l, Z=sum exp(l-m), num=sum v*exp(l-m); summ = num/Z
__global__ void summ_partial(const u16* __restrict__ logits, const u16* __restrict__ vals,
                             float* __restrict__ pm, float* __restrict__ pz,
                             float* __restrict__ pn, int remap)
{
  int tid = threadIdx.x;
  int sc = blockIdx.x, ec = blockIdx.y, b = blockIdx.z;
  int e = ec * 256 + tid;
  float m = -1e30f, z = 0.f, num = 0.f;
  int t0 = b * 4096 + sc * 128;
  for (int si = 0; si < 128; ++si) {
    int t = t0 + si;
    float l = bf2f(logits[(size_t)t * 1024 + e]);
    size_t vrow = remap ? ((size_t)t + 2 * b + 1) : (size_t)t;
    float v = bf2f(vals[vrow * 1024 + e]);
    float mn = fmaxf(m, l);
    float c = __expf(m - mn);
    float p = __expf(l - mn);
    z = z * c + p;
    num = num * c + v * p;
    m = mn;
  }
  int pidx = (((b * 4 + ec) * 32) + sc) * 256 + tid;
  pm[pidx] = m; pz[pidx] = z; pn[pidx] = num;
}

__global__ void summ_combine(const float* __restrict__ pm, const float* __restrict__ pz,
                             const float* __restrict__ pn, float* __restrict__ summ)
{
  int idx = blockIdx.x * 256 + threadIdx.x;  // 0..4095 : b*1024+e
  int b = idx >> 10, e = idx & 1023;
  int ec = e >> 8, tt = e & 255;
  const int base = ((b * 4 + ec) * 32) * 256 + tt;
  float M = -1e30f;
  for (int sc = 0; sc < 32; ++sc) M = fmaxf(M, pm[base + sc * 256]);
  float Z = 0.f, Nm = 0.f;
  for (int sc = 0; sc < 32; ++sc) {
    float w = __expf(pm[base + sc * 256] - M);
    Z += pz[base + sc * 256] * w;
    Nm += pn[base + sc * 256] * w;
  }
  summ[idx] = Nm / Z;
}

// ---------------- elementwise ----------------
// P = O * summ1[b,:];  GP = gelu(P)
__global__ void pk(const u16* __restrict__ O, const float* __restrict__ s1,
                   u16* __restrict__ P, u16* __restrict__ GP)
{
  size_t idx = (size_t)blockIdx.x * 256 + threadIdx.x;   // 2,097,152
  size_t base = idx * 8;
  int t = (int)(base >> 10);
  int b = t >> 12;
  int e = (int)(base & 1023);
  const float* sp = s1 + b * 1024 + e;
  u16x8 ov = *(const u16x8*)(O + base);
  u16x8 pv, gv;
#pragma unroll
  for (int j = 0; j < 8; ++j) {
    float p = bf2f(ov[j]) * sp[j];
    pv[j] = f2bf(p);
    gv[j] = f2bf(geluf(p));
  }
  *(u16x8*)(P + base) = pv;
  *(u16x8*)(GP + base) = gv;
}

// L = silu(G) * summ2[b,:]
__global__ void lk(const u16* __restrict__ G, const float* __restrict__ s2,
                   u16* __restrict__ L)
{
  size_t idx = (size_t)blockIdx.x * 256 + threadIdx.x;
  size_t base = idx * 8;
  int t = (int)(base >> 10);
  int b = t >> 12;
  int e = (int)(base & 1023);
  const float* sp = s2 + b * 1024 + e;
  u16x8 gvv = *(const u16x8*)(G + base);
  u16x8 lv;
#pragma unroll
  for (int j = 0; j < 8; ++j) {
    lv[j] = f2bf(siluf(bf2f(gvv[j])) * sp[j]);
  }
  *(u16x8*)(L + base) = lv;
}

// ---------------- launch ----------------
extern "C" void kernel_launch(void* const* d_in, const int* in_sizes, int n_in,
                              void* d_out, int out_size, void* d_ws, size_t ws_size,
                              hipStream_t stream)
{
  const float* x     = (const float*)d_in[0];
  const float* Wq    = (const float*)d_in[1];
  const float* Wqb   = (const float*)d_in[2];
  const float* Wo    = (const float*)d_in[3];
  const float* Wob   = (const float*)d_in[4];
  const float* Wg    = (const float*)d_in[5];
  const float* Wgb   = (const float*)d_in[6];
  const float* wa    = (const float*)d_in[7];
  const float* wb    = (const float*)d_in[8];
  const float* Wout  = (const float*)d_in[9];
  const float* Woutb = (const float*)d_in[10];
  const float* convw = (const float*)d_in[11];
  const float* convb = (const float*)d_in[12];

  char* ws = (char*)d_ws;
  size_t off = 0;
  auto alloc = [&](size_t bytes) -> char* {
    char* p = ws + off;
    off += (bytes + 255) & ~(size_t)255;
    return p;
  };

  // big slots (aliased lifetimes)
  u16* QPAD = (u16*)alloc((size_t)4 * SPAD * 1024 * 2);   // Qpad -> later Pb
  u16* OB   = (u16*)alloc((size_t)NT * 1024 * 2);         // O    -> later Lb
  u16* GB   = (u16*)alloc((size_t)NT * 1024 * 2);         // G
  u16* XB   = (u16*)alloc((size_t)NT * 1024 * 2);         // x_bf16 -> GA -> GP
  u16* SS   = (u16*)alloc((size_t)NT * 1024 * 2);         // logits A -> logits B
  // weights
  u16* WQB_  = (u16*)alloc((size_t)1024 * 1024 * 2);
  u16* WOB_  = (u16*)alloc((size_t)1024 * 1024 * 2);
  u16* WGB_  = (u16*)alloc((size_t)1024 * 1024 * 2);
  u16* WAB_  = (u16*)alloc((size_t)1024 * 1024 * 2);
  u16* WBB_  = (u16*)alloc((size_t)1024 * 1024 * 2);
  u16* WOUTB_= (u16*)alloc((size_t)1024 * 1024 * 2);
  u16* WCB_  = (u16*)alloc((size_t)1024 * 3072 * 2);
  // reductions
  float* PM = (float*)alloc((size_t)4 * 4 * 32 * 256 * 4);
  float* PZ = (float*)alloc((size_t)4 * 4 * 32 * 256 * 4);
  float* PN = (float*)alloc((size_t)4 * 4 * 32 * 256 * 4);
  float* S1 = (float*)alloc((size_t)4096 * 4);
  float* S2 = (float*)alloc((size_t)4096 * 4);

  if (off > ws_size) return;  // workspace too small -> visible failure (zeros)

  u16* PB = QPAD;  // plain [NT,1024] layout reuse
  u16* GA = XB;
  u16* GP = XB;
  u16* LB = OB;

  const float scale = 0.03125f;  // 1/sqrt(1024)

  // 1. converts
  cvtk<<<16384, 256, 0, stream>>>(x, XB, 4194304, 1.0f);
  cvtk<<<1024, 256, 0, stream>>>(Wq, WQB_, 262144, 1.0f);
  cvtk<<<1024, 256, 0, stream>>>(Wo, WOB_, 262144, 1.0f);
  cvtk<<<1024, 256, 0, stream>>>(Wg, WGB_, 262144, 1.0f);
  cvtk<<<1024, 256, 0, stream>>>(wa, WAB_, 262144, scale);
  cvtk<<<1024, 256, 0, stream>>>(wb, WBB_, 262144, scale);
  cvtk<<<1024, 256, 0, stream>>>(Wout, WOUTB_, 262144, 1.0f);
  cvt_convw<<<4096, 256, 0, stream>>>(convw, WCB_);
  zero_halo<<<32, 256, 0, stream>>>(QPAD);

  // 2. Q/O/G GEMMs (A = x_bf16)
  gemm_k<1><<<1024, 256, 0, stream>>>(XB, WQB_, QPAD, Wqb, NT, 1024, 1024, 1024);
  gemm_k<0><<<1024, 256, 0, stream>>>(XB, WOB_, OB,   Wob, NT, 1024, 1024, 1024);
  gemm_k<0><<<1024, 256, 0, stream>>>(XB, WGB_, GB,   Wgb, NT, 1024, 1024, 1024);

  // 3. conv as GEMM (A = Qpad, K = 3072), epilogue gelu(silu(.)) -> GA
  gemm_k<2><<<1024, 256, 0, stream>>>(QPAD, WCB_, GA, convb, NT, 1024, 3072, 1024);

  // 4. logits A = GA @ (wa*scale)^T -> SS
  gemm_k<0><<<1024, 256, 0, stream>>>(GA, WAB_, SS, nullptr, NT, 1024, 1024, 1024);

  // 5. summ1 = softmax-weighted sum of Q
  {
    dim3 g(32, 4, 4);
    summ_partial<<<g, 256, 0, stream>>>(SS, QPAD, PM, PZ, PN, 1);
    summ_combine<<<16, 256, 0, stream>>>(PM, PZ, PN, S1);
  }

  // 6. P = O * summ1 ; GP = gelu(P)   (PB aliases QPAD, GP aliases XB)
  pk<<<8192, 256, 0, stream>>>(OB, S1, PB, GP);

  // 7. logits B = GP @ (wb*scale)^T -> SS
  gemm_k<0><<<1024, 256, 0, stream>>>(GP, WBB_, SS, nullptr, NT, 1024, 1024, 1024);

  // 8. summ2 = softmax-weighted sum of P
  {
    dim3 g(32, 4, 4);
    summ_partial<<<g, 256, 0, stream>>>(SS, PB, PM, PZ, PN, 0);
    summ_combine<<<16, 256, 0, stream>>>(PM, PZ, PN, S2);
  }

  // 9. L = silu(G) * summ2  (LB aliases OB)
  lk<<<8192, 256, 0, stream>>>(GB, S2, LB);

  // 10. out = L @ Wout^T + b  (fp32)
  gemm_k<3><<<1024, 256, 0, stream>>>(LB, WOUTB_, d_out, Woutb, NT, 1024, 1024, 1024);
}